// Round 3
// baseline (341.026 us; speedup 1.0000x reference)
//
#include <hip/hip_runtime.h>
#include <hip/hip_bf16.h>

#define BATCH 8
#define NN    2048
#define FIN   512
#define FOUT  32
#define GALPHA 0.2f
#define RT    32          // rows per k_main block
#define NIT   32          // 2048 / 64 k-intervals

typedef float  f32x4  __attribute__((ext_vector_type(4)));
typedef __bf16 bf16x8 __attribute__((ext_vector_type(8)));
typedef unsigned short u16;
typedef u16 u16x8 __attribute__((ext_vector_type(8)));

static __device__ __forceinline__ u16 f2bf(float f) {
    __hip_bfloat16 h = __float2bfloat16(f);
    union { __hip_bfloat16 h; u16 u; } c; c.h = h; return c.u;
}
static __device__ __forceinline__ float bf2f(u16 u) {
    union { u16 u; __hip_bfloat16 h; } c; c.u = u; return __bfloat162float(c.h);
}

// K0: w1[i] = sum_o Wfc[o][i]*a1[o], w2 likewise. 1 block x 512 thr. fp32 in.
__global__ void k_w12(const float* __restrict__ Wfc,
                      const float* __restrict__ Wat,
                      float* __restrict__ w1, float* __restrict__ w2) {
    int i = threadIdx.x;            // 0..511
    float s1 = 0.f, s2 = 0.f;
    #pragma unroll
    for (int o = 0; o < FOUT; o++) {
        float wv = Wfc[o * FIN + i];
        s1 += wv * Wat[o];
        s2 += wv * Wat[FOUT + o];
    }
    w1[i] = s1; w2[i] = s2;
}

// K1: fused transpose + f1/f2 partial dots.
// xt[b][i][m] = bf16(x[b][m][i]); f1/f2 accumulated via atomicAdd from fp32 x.
// grid 8 it x 32 mt x 8 b = 2048 blocks x 256 thr.
__global__ void k_xtf(const float* __restrict__ x,
                      const float* __restrict__ w1, const float* __restrict__ w2,
                      __hip_bfloat16* __restrict__ xt,
                      float* __restrict__ f1, float* __restrict__ f2) {
    int bx = blockIdx.x;
    int it = bx & 7, mt = (bx >> 3) & 31, b = bx >> 8;
    int m0 = mt * 64, i0 = it * 64;
    __shared__ u16 tile[64][72];
    int tt = threadIdx.x;
    int mm = tt >> 3;              // 0..31
    int ic = (tt & 7) * 8;         // 0..56
    const float* xb = x + ((size_t)b * NN + m0) * FIN + i0;
    const f32x4* w1p = (const f32x4*)(w1 + i0 + ic);
    const f32x4* w2p = (const f32x4*)(w2 + i0 + ic);
    f32x4 wA = w1p[0], wB = w1p[1], wC = w2p[0], wD = w2p[1];
    float p1[2], p2[2];
    #pragma unroll
    for (int h = 0; h < 2; h++) {
        int m = mm + h * 32;
        const f32x4* src = (const f32x4*)(xb + (size_t)m * FIN + ic);
        f32x4 v0 = src[0], v1 = src[1];
        u16x8 pk;
        float s1 = 0.f, s2 = 0.f;
        #pragma unroll
        for (int j = 0; j < 4; j++) {
            pk[j] = f2bf(v0[j]); pk[4 + j] = f2bf(v1[j]);
            s1 += v0[j] * wA[j] + v1[j] * wB[j];
            s2 += v0[j] * wC[j] + v1[j] * wD[j];
        }
        p1[h] = s1; p2[h] = s2;
        *(u16x8*)&tile[m][ic] = pk;
    }
    // reduce partial dots across the 8 i-chunk threads of each row
    #pragma unroll
    for (int off = 1; off < 8; off <<= 1) {
        p1[0] += __shfl_xor(p1[0], off); p1[1] += __shfl_xor(p1[1], off);
        p2[0] += __shfl_xor(p2[0], off); p2[1] += __shfl_xor(p2[1], off);
    }
    if ((tt & 7) == 0) {
        size_t r0 = (size_t)b * NN + m0 + mm;
        atomicAdd(&f1[r0], p1[0]);      atomicAdd(&f1[r0 + 32], p1[1]);
        atomicAdd(&f2[r0], p2[0]);      atomicAdd(&f2[r0 + 32], p2[1]);
    }
    __syncthreads();
    __hip_bfloat16* xtb = xt + ((size_t)b * FIN + i0) * NN + m0;
    int mc = (tt & 7) * 8;
    #pragma unroll
    for (int h = 0; h < 2; h++) {
        int ii = (tt >> 3) + h * 32;
        u16x8 v;
        #pragma unroll
        for (int j = 0; j < 8; j++) v[j] = tile[mc + j][ii];
        *(u16x8*)(xtb + (size_t)ii * NN + mc) = v;
    }
}

// K2: fused attn-gen + GEMM + softmax-normalize + ELU. fp32 out.
// grid 512 (b = blk&7 -> XCD affinity, rowtile = blk>>3) -> 2 blocks/CU.
// Block: 32 rows x 512 cols; k-interval BK=64 (2 MFMA k-steps per barrier).
__global__ __launch_bounds__(512, 4) void k_main(
    const int* __restrict__ adj, const __hip_bfloat16* __restrict__ xt,
    const float* __restrict__ f1, const float* __restrict__ f2,
    float* __restrict__ out)
{
    const int bx = blockIdx.x;
    const int b = bx & 7, rt = bx >> 3;
    const int n0 = rt * RT;
    const int tid = threadIdx.x;
    const int lane = tid & 63, wv = tid >> 6;
    const int quad = lane >> 4, l15 = lane & 15;

    // A tile: [row][kk^ (8*(row&7))] u16 — XOR swizzle, 16B-aligned frags,
    // conflict-free writes, minimum-phase b128 reads.
    __shared__ u16 At[2][RT * 64];
    __shared__ float rs[RT];

    // --- A-generation role: thread -> (row = tid>>4, m-chunk = (tid&15)*4) ---
    const int grow = tid >> 4;          // 0..31
    const int gch  = (tid & 15) * 4;    // 0..60
    const int wofs = grow * 64 + (gch ^ (8 * (grow & 7)));
    const int*   adjp = adj + ((size_t)b * NN + (n0 + grow)) * NN + gch;
    const float* f2p  = f2 + b * NN + gch;
    const float  f1v  = f1[b * NN + n0 + grow];
    float rpart = 0.f;

    // --- MFMA role: wave wv owns cols [wv*64, wv*64+64) ---
    const __hip_bfloat16* xtp = xt + ((size_t)(b * FIN) + wv * 64 + l15) * NN + quad * 8;

    f32x4 acc[2][4];
    #pragma unroll
    for (int s = 0; s < 2; s++)
        #pragma unroll
        for (int c = 0; c < 4; c++)
            acc[s][c] = (f32x4){0.f, 0.f, 0.f, 0.f};

    auto gen = [&](int buf, int4 av, float4 fv) {
        const int*   ai = (const int*)&av;
        const float* fi = (const float*)&fv;
        ushort4 pk;
        u16* pp = (u16*)&pk;
        #pragma unroll
        for (int j = 0; j < 4; j++) {
            float s  = f1v + fi[j];
            float ls = fmaxf(s, GALPHA * s);          // leaky_relu
            float ev = (ai[j] != 0) ? __expf(ls) : 0.f;
            u16 hb = f2bf(ev);
            rpart += bf2f(hb);                        // rowsum from bf16-rounded value
            pp[j] = hb;
        }
        *(ushort4*)&At[buf][wofs] = pk;
    };

    // prologue: gen tile 0; issue adj/f2 for tiles 1 and 2 (depth-2 ring)
    int4   a0 = *(const int4*)adjp;
    float4 g0 = *(const float4*)f2p;
    int4   aring[2];
    float4 fring[2];
    gen(0, a0, g0);
    aring[1] = *(const int4*)(adjp + 64);
    fring[1] = *(const float4*)(f2p + 64);
    aring[0] = *(const int4*)(adjp + 128);
    fring[0] = *(const float4*)(f2p + 128);
    __syncthreads();

    #pragma unroll 2
    for (int t = 0; t < NIT; t++) {
        const int cur = t & 1;
        // B fragments for both k-steps of this interval (L2-resident xt)
        const __hip_bfloat16* xk = xtp + t * 64;
        bf16x8 B0[4], B1[4];
        #pragma unroll
        for (int c = 0; c < 4; c++) {
            B0[c] = *(const bf16x8*)(xk + (size_t)(c * 16) * NN);
            B1[c] = *(const bf16x8*)(xk + 32 + (size_t)(c * 16) * NN);
        }
        #pragma unroll
        for (int s = 0; s < 2; s++) {
            const int rsw = 8 * ((s * 16 + l15) & 7);
            bf16x8 Af0 = *(const bf16x8*)&At[cur][(s * 16 + l15) * 64 + ((quad * 8) ^ rsw)];
            #pragma unroll
            for (int c = 0; c < 4; c++)
                acc[s][c] = __builtin_amdgcn_mfma_f32_16x16x32_bf16(Af0, B0[c], acc[s][c], 0, 0, 0);
        }
        #pragma unroll
        for (int s = 0; s < 2; s++) {
            const int rsw = 8 * ((s * 16 + l15) & 7);
            bf16x8 Af1 = *(const bf16x8*)&At[cur][(s * 16 + l15) * 64 + ((32 + quad * 8) ^ rsw)];
            #pragma unroll
            for (int c = 0; c < 4; c++)
                acc[s][c] = __builtin_amdgcn_mfma_f32_16x16x32_bf16(Af1, B1[c], acc[s][c], 0, 0, 0);
        }
        if (t < NIT - 1) {
            gen(1 - cur, aring[(t + 1) & 1], fring[(t + 1) & 1]);   // tile t+1
            if (t < NIT - 3) {                                      // refill ring: tile t+3
                aring[(t + 1) & 1] = *(const int4*)(adjp + (size_t)(t + 3) * 64);
                fring[(t + 1) & 1] = *(const float4*)(f2p + (size_t)(t + 3) * 64);
            }
        }
        // LDS-only barrier: global prefetches stay in flight (no vmcnt drain)
        asm volatile("s_waitcnt lgkmcnt(0)\ns_barrier" ::: "memory");
    }

    // rowsum: reduce over the 16 m-chunk threads of each row
    #pragma unroll
    for (int off = 1; off < 16; off <<= 1) rpart += __shfl_xor(rpart, off);
    if ((tid & 15) == 0) rs[grow] = 1.0f / rpart;
    __syncthreads();

    // epilogue: normalize, ELU, store fp32
    #pragma unroll
    for (int s = 0; s < 2; s++) {
        #pragma unroll
        for (int r = 0; r < 4; r++) {
            const int row = s * 16 + quad * 4 + r;
            const float inv = rs[row];
            float* op = out + ((size_t)b * NN + (n0 + row)) * FIN + wv * 64 + l15;
            #pragma unroll
            for (int c = 0; c < 4; c++) {
                float v = acc[s][c][r] * inv;
                v = v > 0.f ? v : (__expf(v) - 1.f);   // elu
                op[c * 16] = v;
            }
        }
    }
}

extern "C" void kernel_launch(void* const* d_in, const int* in_sizes, int n_in,
                              void* d_out, int out_size, void* d_ws, size_t ws_size,
                              hipStream_t stream) {
    const float* x   = (const float*)d_in[0];
    const int*   adj = (const int*)d_in[1];
    const float* Wfc = (const float*)d_in[2];
    const float* Wat = (const float*)d_in[3];
    float* out = (float*)d_out;

    float* w1 = (float*)d_ws;                       // 512
    float* w2 = w1 + 512;                           // 512
    float* f1 = w2 + 512;                           // 8*2048
    float* f2 = f1 + BATCH * NN;                    // 8*2048
    __hip_bfloat16* xt = (__hip_bfloat16*)(f2 + BATCH * NN);   // 8*512*2048 bf16 (~16.8 MB)

    hipMemsetAsync(f1, 0, (size_t)2 * BATCH * NN * sizeof(float), stream);
    hipLaunchKernelGGL(k_w12, dim3(1),    dim3(512), 0, stream, Wfc, Wat, w1, w2);
    hipLaunchKernelGGL(k_xtf, dim3(2048), dim3(256), 0, stream, x, w1, w2, xt, f1, f2);
    hipLaunchKernelGGL(k_main, dim3(512), dim3(512), 0, stream, adj, xt, f1, f2, out);
}

// Round 4
// 285.948 us; speedup vs baseline: 1.1926x; 1.1926x over previous
//
#include <hip/hip_runtime.h>
#include <hip/hip_bf16.h>

#define BATCH 8
#define NN    2048
#define FIN   512
#define FOUT  32
#define GALPHA 0.2f
#define NROW  128         // n-rows per k_main block
#define NIT   32          // 2048/64 k-intervals

typedef float  f32x4  __attribute__((ext_vector_type(4)));
typedef __bf16 bf16x8 __attribute__((ext_vector_type(8)));
typedef unsigned short u16;
typedef u16 u16x8 __attribute__((ext_vector_type(8)));

static __device__ __forceinline__ u16 f2bf(float f) {
    __hip_bfloat16 h = __float2bfloat16(f);
    union { __hip_bfloat16 h; u16 u; } c; c.h = h; return c.u;
}
static __device__ __forceinline__ float bf2f(u16 u) {
    union { u16 u; __hip_bfloat16 h; } c; c.u = u; return __bfloat162float(c.h);
}

// K0: w1[i] = sum_o Wfc[o][i]*a1[o], w2 likewise. 1 block x 512 thr. fp32 in.
__global__ void k_w12(const float* __restrict__ Wfc,
                      const float* __restrict__ Wat,
                      float* __restrict__ w1, float* __restrict__ w2) {
    int i = threadIdx.x;
    float s1 = 0.f, s2 = 0.f;
    #pragma unroll
    for (int o = 0; o < FOUT; o++) {
        float wv = Wfc[o * FIN + i];
        s1 += wv * Wat[o];
        s2 += wv * Wat[FOUT + o];
    }
    w1[i] = s1; w2[i] = s2;
}

// K1: fused transpose + f1/f2 partial dots (verified R3). grid 2048 x 256.
__global__ void k_xtf(const float* __restrict__ x,
                      const float* __restrict__ w1, const float* __restrict__ w2,
                      __hip_bfloat16* __restrict__ xt,
                      float* __restrict__ f1, float* __restrict__ f2) {
    int bx = blockIdx.x;
    int it = bx & 7, mt = (bx >> 3) & 31, b = bx >> 8;
    int m0 = mt * 64, i0 = it * 64;
    __shared__ u16 tile[64][72];
    int tt = threadIdx.x;
    int mm = tt >> 3;
    int ic = (tt & 7) * 8;
    const float* xb = x + ((size_t)b * NN + m0) * FIN + i0;
    const f32x4* w1p = (const f32x4*)(w1 + i0 + ic);
    const f32x4* w2p = (const f32x4*)(w2 + i0 + ic);
    f32x4 wA = w1p[0], wB = w1p[1], wC = w2p[0], wD = w2p[1];
    float p1[2], p2[2];
    #pragma unroll
    for (int h = 0; h < 2; h++) {
        int m = mm + h * 32;
        const f32x4* src = (const f32x4*)(xb + (size_t)m * FIN + ic);
        f32x4 v0 = src[0], v1 = src[1];
        u16x8 pk;
        float s1 = 0.f, s2 = 0.f;
        #pragma unroll
        for (int j = 0; j < 4; j++) {
            pk[j] = f2bf(v0[j]); pk[4 + j] = f2bf(v1[j]);
            s1 += v0[j] * wA[j] + v1[j] * wB[j];
            s2 += v0[j] * wC[j] + v1[j] * wD[j];
        }
        p1[h] = s1; p2[h] = s2;
        *(u16x8*)&tile[m][ic] = pk;
    }
    #pragma unroll
    for (int off = 1; off < 8; off <<= 1) {
        p1[0] += __shfl_xor(p1[0], off); p1[1] += __shfl_xor(p1[1], off);
        p2[0] += __shfl_xor(p2[0], off); p2[1] += __shfl_xor(p2[1], off);
    }
    if ((tt & 7) == 0) {
        size_t r0 = (size_t)b * NN + m0 + mm;
        atomicAdd(&f1[r0], p1[0]);      atomicAdd(&f1[r0 + 32], p1[1]);
        atomicAdd(&f2[r0], p2[0]);      atomicAdd(&f2[r0 + 32], p2[1]);
    }
    __syncthreads();
    __hip_bfloat16* xtb = xt + ((size_t)b * FIN + i0) * NN + m0;
    int mc = (tt & 7) * 8;
    #pragma unroll
    for (int h = 0; h < 2; h++) {
        int ii = (tt >> 3) + h * 32;
        u16x8 v;
        #pragma unroll
        for (int j = 0; j < 8; j++) v[j] = tile[mc + j][ii];
        *(u16x8*)(xtb + (size_t)ii * NN + mc) = v;
    }
}

// K2: bit-pack adj (0/1 int32) -> 1 bit. Wave per row-quarter... wave per row:
// grid 4096 x 256 (4 rows/block). Lane owns m in [lane*32, lane*32+32).
__global__ void k_pack(const int* __restrict__ adj, unsigned int* __restrict__ bits) {
    int row  = blockIdx.x * 4 + (threadIdx.x >> 6);   // 0..16383
    int lane = threadIdx.x & 63;
    const int* p = adj + (size_t)row * NN + lane * 32;
    unsigned int bv = 0;
    #pragma unroll
    for (int j = 0; j < 8; j++) {
        int4 v = *(const int4*)(p + j * 4);
        bv |= (v.x != 0 ? 1u : 0u) << (j * 4 + 0);
        bv |= (v.y != 0 ? 1u : 0u) << (j * 4 + 1);
        bv |= (v.z != 0 ? 1u : 0u) << (j * 4 + 2);
        bv |= (v.w != 0 ? 1u : 0u) << (j * 4 + 3);
    }
    bits[(size_t)row * 64 + lane] = bv;
}

// K3: fused attn-gen + GEMM + softmax-normalize + ELU.
// grid 256 = 16 rt x 2 it x 8 b (b = bx&7 -> XCD affinity). 512 thr / 8 waves.
// Block: 128 rows x 256 cols; interval BK=64; adj-bits dup=2, xt traffic 256 MB.
__global__ __launch_bounds__(512, 2) void k_main(
    const unsigned int* __restrict__ bits, const __hip_bfloat16* __restrict__ xt,
    const float* __restrict__ f1, const float* __restrict__ f2,
    float* __restrict__ out)
{
    const int bx = blockIdx.x;
    const int b = bx & 7, rt = (bx >> 3) & 15, it = bx >> 7;
    const int n0 = rt * NROW;
    const int i0 = it * 256;
    const int tid = threadIdx.x;
    const int lane = tid & 63, wv = tid >> 6;
    const int quad = lane >> 4, l15 = lane & 15;

    // A tile: [row][octet ^ (row&7)] u16, row stride 64 (128B) — R3-verified swizzle.
    __shared__ u16 At[2][NROW * 64];     // 2 x 16 KB
    __shared__ float rs[NROW];

    // --- gen role: thread -> (row = tid>>2, m-quarter q4 = tid&3, 16 m each) ---
    const int grow = tid >> 2;           // 0..127
    const int q4   = tid & 3;
    const unsigned short* bp = (const unsigned short*)bits
                               + ((size_t)(b * NN) + n0 + grow) * 128 + q4;  // +4 per interval
    const float* f2p = f2 + b * NN + q4 * 16;                                 // +64 per interval
    const float  f1v = f1[b * NN + n0 + grow];
    const int swz = grow & 7;
    u16* wp0 = &At[0][grow * 64 + (((q4 * 2) ^ swz) * 8)];
    u16* wp1 = &At[0][grow * 64 + (((q4 * 2 + 1) ^ swz) * 8)];
    float rpart = 0.f;

    // --- MFMA role: wave wv owns i-cols [i0 + wv*32, +32), 2 col-tiles ---
    const __hip_bfloat16* xtp = xt + ((size_t)(b * FIN) + i0 + wv * 32 + l15) * NN + quad * 8;

    f32x4 acc[8][2];
    #pragma unroll
    for (int s = 0; s < 8; s++) { acc[s][0] = (f32x4){0,0,0,0}; acc[s][1] = (f32x4){0,0,0,0}; }

    auto gen = [&](int buf, unsigned int bv, const f32x4* fr) {
        u16x8 pk0, pk1;
        #pragma unroll
        for (int e = 0; e < 16; e++) {
            float s  = f1v + fr[e >> 2][e & 3];
            float ls = fmaxf(s, GALPHA * s);                 // leaky_relu
            float ev = ((bv >> e) & 1u) ? __expf(ls) : 0.f;
            u16 hb = f2bf(ev);
            rpart += bf2f(hb);                               // rowsum of bf16-rounded
            if (e < 8) pk0[e] = hb; else pk1[e - 8] = hb;
        }
        *(u16x8*)(wp0 + buf * (NROW * 64)) = pk0;
        *(u16x8*)(wp1 + buf * (NROW * 64)) = pk1;
    };

    // prologue: gen tile 0 (direct loads); prime rings for tiles 1,2; B for t=0
    {
        unsigned int b0 = bp[0];
        f32x4 g0[4];
        #pragma unroll
        for (int j = 0; j < 4; j++) g0[j] = *(const f32x4*)(f2p + j * 4);
        gen(0, b0, g0);
    }
    unsigned int brng[2];
    f32x4 frng[2][4];
    brng[1] = bp[4];
    #pragma unroll
    for (int j = 0; j < 4; j++) frng[1][j] = *(const f32x4*)(f2p + 64 + j * 4);
    brng[0] = bp[8];
    #pragma unroll
    for (int j = 0; j < 4; j++) frng[0][j] = *(const f32x4*)(f2p + 128 + j * 4);

    bf16x8 Bc[2][2], Bn[2][2];
    #pragma unroll
    for (int ks = 0; ks < 2; ks++)
        #pragma unroll
        for (int c = 0; c < 2; c++)
            Bc[ks][c] = *(const bf16x8*)(xtp + ks * 32 + (size_t)(c * 16) * NN);
    __syncthreads();

    #pragma unroll 2
    for (int t = 0; t < NIT; t++) {
        const int cur = t & 1;
        if (t < NIT - 1) {   // B prefetch for t+1 (consumed after next barrier)
            const __hip_bfloat16* xk = xtp + (t + 1) * 64;
            #pragma unroll
            for (int ks = 0; ks < 2; ks++)
                #pragma unroll
                for (int c = 0; c < 2; c++)
                    Bn[ks][c] = *(const bf16x8*)(xk + ks * 32 + (size_t)(c * 16) * NN);
        }
        #pragma unroll
        for (int ks = 0; ks < 2; ks++) {
            #pragma unroll
            for (int s = 0; s < 8; s++) {
                const int row = s * 16 + l15;
                bf16x8 Af = *(const bf16x8*)&At[cur][row * 64 + (((ks * 4 + quad) ^ (row & 7)) * 8)];
                acc[s][0] = __builtin_amdgcn_mfma_f32_16x16x32_bf16(Af, Bc[ks][0], acc[s][0], 0, 0, 0);
                acc[s][1] = __builtin_amdgcn_mfma_f32_16x16x32_bf16(Af, Bc[ks][1], acc[s][1], 0, 0, 0);
            }
        }
        if (t < NIT - 1) {
            gen(1 - cur, brng[(t + 1) & 1], frng[(t + 1) & 1]);   // tile t+1
            if (t < NIT - 2) {                                    // refill ring: tile t+2
                brng[t & 1] = bp[(t + 2) * 4];
                #pragma unroll
                for (int j = 0; j < 4; j++)
                    frng[t & 1][j] = *(const f32x4*)(f2p + (t + 2) * 64 + j * 4);
            }
        }
        // LDS-only barrier: global prefetches stay in flight (no vmcnt drain)
        asm volatile("s_waitcnt lgkmcnt(0)\ns_barrier" ::: "memory");
        #pragma unroll
        for (int ks = 0; ks < 2; ks++) {
            Bc[ks][0] = Bn[ks][0]; Bc[ks][1] = Bn[ks][1];
        }
    }

    // rowsum: reduce over the 4 m-quarter threads of each row
    rpart += __shfl_xor(rpart, 1);
    rpart += __shfl_xor(rpart, 2);
    if (q4 == 0) rs[grow] = 1.0f / rpart;
    __syncthreads();

    // epilogue: normalize, ELU, store fp32
    #pragma unroll
    for (int s = 0; s < 8; s++) {
        #pragma unroll
        for (int r = 0; r < 4; r++) {
            const int row = s * 16 + quad * 4 + r;
            const float inv = rs[row];
            float* op = out + ((size_t)b * NN + (n0 + row)) * FIN + i0 + wv * 32 + l15;
            #pragma unroll
            for (int c = 0; c < 2; c++) {
                float v = acc[s][c][r] * inv;
                v = v > 0.f ? v : (__expf(v) - 1.f);   // elu
                op[c * 16] = v;
            }
        }
    }
}

extern "C" void kernel_launch(void* const* d_in, const int* in_sizes, int n_in,
                              void* d_out, int out_size, void* d_ws, size_t ws_size,
                              hipStream_t stream) {
    const float* x   = (const float*)d_in[0];
    const int*   adj = (const int*)d_in[1];
    const float* Wfc = (const float*)d_in[2];
    const float* Wat = (const float*)d_in[3];
    float* out = (float*)d_out;

    float* w1 = (float*)d_ws;                                   // 512
    float* w2 = w1 + 512;                                       // 512
    float* f1 = w2 + 512;                                       // 16384
    float* f2 = f1 + BATCH * NN;                                // 16384
    unsigned int* bits = (unsigned int*)(f2 + BATCH * NN);      // 16384*64 u32 = 4.2 MB
    __hip_bfloat16* xt = (__hip_bfloat16*)(bits + (size_t)BATCH * NN * 64);  // 16.8 MB

    hipMemsetAsync(f1, 0, (size_t)2 * BATCH * NN * sizeof(float), stream);
    hipLaunchKernelGGL(k_w12,  dim3(1),    dim3(512), 0, stream, Wfc, Wat, w1, w2);
    hipLaunchKernelGGL(k_xtf,  dim3(2048), dim3(256), 0, stream, x, w1, w2, xt, f1, f2);
    hipLaunchKernelGGL(k_pack, dim3(4096), dim3(256), 0, stream, adj, bits);
    hipLaunchKernelGGL(k_main, dim3(256),  dim3(512), 0, stream, bits, xt, f1, f2, out);
}